// Round 3
// baseline (1671.372 us; speedup 1.0000x reference)
//
#include <hip/hip_runtime.h>

// Adaptive separable conv (SepConv): out[b,c,y,x] = sum_i sum_j inp[b,c,y+i,x+j]*v[b,i,y,x]*h[b,j,y,x]
// B=2,C=3,H=W=256,K=51. fp32 in/out. No MFMA path (per-pixel weights; no fp32 MFMA on CDNA4).
//
// R3: channel -> grid.z (6 slices). R1/R2 showed 512-thread blocks get a pathological
// 64-VGPR budget (spill: WRITE 153MB). Fix by shrinking the problem per block instead of
// fighting the allocator:
//  - 1 channel/block: LDS 19.5KB (was 58.5), live regs ~84 (was ~105+), 256-thread blocks
//    (known-good allocator path from R0: VGPR=172, zero spill).
//  - Separable factorization per i-block: t[rx] = sum_ib v[ib]*w[ib], acc += h*t
//    -> 1.25 VALU ops/MAC (was 1.33 via channel hoisting, 2.0 unhoisted).
//  - i-split NS=4 (13/13/13/12 taps); main loop = uniform 3 BI=4 blocks, BI=1 tail for s<3.
// Occupancy target: 4-5 waves/SIMD (VGPR-limited), vs 2 in R0.

namespace {
constexpr int KK = 51;
constexpr int NB = 2;
constexpr int NC = 3;
constexpr int HH = 256;
constexpr int WW = 256;
constexpr int IN_H = HH + KK - 1;   // 306
constexpr int IN_W = WW + KK - 1;   // 306

constexpr int TILE_W = 32;          // output cols per block
constexpr int TILE_H = 8;           // output rows per block
constexpr int NTX = 8;              // threads along x (each covers R=4 outputs)
constexpr int R = 4;
constexpr int NTY = 8;
constexpr int NS = 4;               // i-tap split (one range per wave)
constexpr int NTHREADS = NTX * NTY * NS;   // 256
constexpr int HALO_W = TILE_W + KK - 1;  // 82
constexpr int LDS_W = 84;           // 82 valid + 2 zero-pad cols; 84 mod 32 = 20 (conflict-friendly)
constexpr int LDS_H = TILE_H + KK - 1;   // 58
constexpr int BI = 4;               // i-taps per register block
constexpr int KSTRIDE = HH * WW;    // per-tap stride in v/h
}

__device__ __forceinline__ float fget(const float4 v, int i) {
  return (i == 0) ? v.x : (i == 1) ? v.y : (i == 2) ? v.z : v.w;
}

__global__ __launch_bounds__(NTHREADS, 4)   // cap 128 VGPR, min 4 waves/EU
void sepconv_kernel(
    const float* __restrict__ inp,
    const float* __restrict__ vert,
    const float* __restrict__ horiz,
    float* __restrict__ out)
{
  __shared__ float lds[LDS_H * LDS_W];   // 19,488 B

  const int tid = threadIdx.x;
  const int tx  = tid & (NTX - 1);
  const int ty  = (tid >> 3) & (NTY - 1);
  const int s   = tid >> 6;                    // wave id: 0..3 (wave-uniform)

  const int x0 = blockIdx.x * TILE_W;
  const int y0 = blockIdx.y * TILE_H;
  const int bc = blockIdx.z;                   // 0..5
  const int b  = bc / NC;
  const int c  = bc % NC;

  // ---- Stage input tile: 1ch x 58 rows x 82 cols (float2), zero the 2 pad cols.
  {
    const float* src = inp + (((size_t)(b * NC + c)) * IN_H + y0) * IN_W + x0;
    constexpr int total2 = LDS_H * (HALO_W / 2);   // 58*41 = 2378
    for (int e = tid; e < total2; e += NTHREADS) {
      const int col2 = e % (HALO_W / 2);
      const int r    = e / (HALO_W / 2);
      const float2 v = *reinterpret_cast<const float2*>(src + (size_t)r * IN_W + col2 * 2);
      float* dst = &lds[r * LDS_W + col2 * 2];
      dst[0] = v.x; dst[1] = v.y;
    }
    for (int e = tid; e < LDS_H * 2; e += NTHREADS) {
      const int r = e >> 1;
      const int p = e & 1;
      lds[r * LDS_W + HALO_W + p] = 0.0f;
    }
  }
  __syncthreads();

  const int lx = tx * R;                 // local LDS col base (16B aligned)
  const int xg = x0 + lx;                // global x of first output
  const int yg = y0 + ty;                // global y

  float acc[R] = {0.f, 0.f, 0.f, 0.f};

  // i-tap split: s<3 -> 13 taps (3 BI=4 blocks + 1 tail), s==3 -> 12 taps (3 blocks)
  const int sbase = 13 * s - ((s == 3) ? 1 : 0);   // 0,13,26,38
  // s=3 gets taps 39..50 (12). Recompute cleanly:
  const int sb = (s < 3) ? 13 * s : 39;
  const bool has_tail = (s < 3);

  const float* vbase = vert  + (((size_t)b * KK) * HH + yg) * WW + xg;
  const float* hbase = horiz + (((size_t)b * KK) * HH + yg) * WW + xg;
  (void)sbase;

  for (int i0 = 0; i0 < 3; ++i0) {       // uniform across all waves; all taps valid
    const int ibase = sb + i0 * BI;

    // Vertical weights for this block (read-once).
    float4 v4[BI];
#pragma unroll
    for (int ib = 0; ib < BI; ++ib)
      v4[ib] = *reinterpret_cast<const float4*>(vbase + (size_t)(ibase + ib) * KSTRIDE);

    // Rolling windows: w[ib] = inp row (ty+ibase+ib), cols [lx, lx+8)
    float w[BI][8];
#pragma unroll
    for (int ib = 0; ib < BI; ++ib) {
      const int rr = ty + ibase + ib;    // <= 7 + 50 = 57, in bounds
      const float4* p = reinterpret_cast<const float4*>(&lds[rr * LDS_W + lx]);
      const float4 a = p[0], bq = p[1];
      w[ib][0] = a.x;  w[ib][1] = a.y;  w[ib][2] = a.z;  w[ib][3] = a.w;
      w[ib][4] = bq.x; w[ib][5] = bq.y; w[ib][6] = bq.z; w[ib][7] = bq.w;
    }

    // h for chunk j0=0 (taps 0..3)
    float4 h4[4];
#pragma unroll
    for (int jj = 0; jj < 4; ++jj)
      h4[jj] = *reinterpret_cast<const float4*>(hbase + (size_t)jj * KSTRIDE);

    for (int j0 = 0; j0 < 52; j0 += 4) {   // 13 chunks of 4 j-taps
#pragma unroll
      for (int jj = 0; jj < 4; ++jj) {
        // t = sum_ib v[ib]*w[ib][rx+jj]; acc += h*t  -> (BI+1) ops per BI MACs
#pragma unroll
        for (int rx = 0; rx < R; ++rx) {
          float t = fget(v4[0], rx) * w[0][rx + jj];
#pragma unroll
          for (int ib = 1; ib < BI; ++ib)
            t = fmaf(fget(v4[ib], rx), w[ib][rx + jj], t);
          acc[rx] = fmaf(fget(h4[jj], rx), t, acc[rx]);
        }
        // In-place prefetch of next chunk's tap jj (clamped; dead on last chunk, harmless).
        const int j  = j0 + 4 + jj;
        const int jc = (j <= 50) ? j : 50;
        float4 t4 = *reinterpret_cast<const float4*>(hbase + (size_t)jc * KSTRIDE);
        if (j > 50) t4 = make_float4(0.f, 0.f, 0.f, 0.f);
        h4[jj] = t4;
      }

      // Rotate windows; read next quad (max col = 28+44+8+3 = 83, zero pad region).
      if (j0 < 48) {
#pragma unroll
        for (int ib = 0; ib < BI; ++ib) {
          const int rr = ty + ibase + ib;
#pragma unroll
          for (int q = 0; q < 4; ++q) w[ib][q] = w[ib][q + 4];
          const float4 n = *reinterpret_cast<const float4*>(&lds[rr * LDS_W + lx + j0 + 8]);
          w[ib][4] = n.x; w[ib][5] = n.y; w[ib][6] = n.z; w[ib][7] = n.w;
        }
      }
    }
  }

  // ---- BI=1 tail: 13th tap for s<3 (i = sb+12; 2 ops/MAC but only 1/13 of work)
  if (has_tail) {
    const int i = sb + 12;               // 12, 25, 38
    const float4 v1 = *reinterpret_cast<const float4*>(vbase + (size_t)i * KSTRIDE);
    const int rr = ty + i;               // <= 45
    float w1[8];
    {
      const float4* p = reinterpret_cast<const float4*>(&lds[rr * LDS_W + lx]);
      const float4 a = p[0], bq = p[1];
      w1[0] = a.x;  w1[1] = a.y;  w1[2] = a.z;  w1[3] = a.w;
      w1[4] = bq.x; w1[5] = bq.y; w1[6] = bq.z; w1[7] = bq.w;
    }
    float4 h4[4];
#pragma unroll
    for (int jj = 0; jj < 4; ++jj)
      h4[jj] = *reinterpret_cast<const float4*>(hbase + (size_t)jj * KSTRIDE);

    for (int j0 = 0; j0 < 52; j0 += 4) {
#pragma unroll
      for (int jj = 0; jj < 4; ++jj) {
#pragma unroll
        for (int rx = 0; rx < R; ++rx)
          acc[rx] = fmaf(fget(v1, rx) * fget(h4[jj], rx), w1[rx + jj], acc[rx]);
        const int j  = j0 + 4 + jj;
        const int jc = (j <= 50) ? j : 50;
        float4 t4 = *reinterpret_cast<const float4*>(hbase + (size_t)jc * KSTRIDE);
        if (j > 50) t4 = make_float4(0.f, 0.f, 0.f, 0.f);
        h4[jj] = t4;
      }
      if (j0 < 48) {
#pragma unroll
        for (int q = 0; q < 4; ++q) w1[q] = w1[q + 4];
        const float4 n = *reinterpret_cast<const float4*>(&lds[rr * LDS_W + lx + j0 + 8]);
        w1[4] = n.x; w1[5] = n.y; w1[6] = n.z; w1[7] = n.w;
      }
    }
  }

  // ---- Reduce the 4 i-split partials (waves 1..3 -> LDS, wave 0 adds & stores)
  __syncthreads();   // all LDS inp reads done; safe to reuse (3*64*4*4B = 3KB)
  if (s > 0) {
    float* p = &lds[((s - 1) * 64 + ty * NTX + tx) * 4];
#pragma unroll
    for (int rx = 0; rx < R; ++rx) p[rx] = acc[rx];
  }
  __syncthreads();
  if (s == 0) {
#pragma unroll
    for (int g = 0; g < 3; ++g) {
      const float* p = &lds[(g * 64 + ty * NTX + tx) * 4];
#pragma unroll
      for (int rx = 0; rx < R; ++rx) acc[rx] += p[rx];
    }
    const float4 o = make_float4(acc[0], acc[1], acc[2], acc[3]);
    *reinterpret_cast<float4*>(out + (((size_t)(b * NC + c)) * HH + yg) * WW + xg) = o;
  }
}

extern "C" void kernel_launch(void* const* d_in, const int* in_sizes, int n_in,
                              void* d_out, int out_size, void* d_ws, size_t ws_size,
                              hipStream_t stream) {
  const float* inp   = (const float*)d_in[0];
  const float* vert  = (const float*)d_in[1];
  const float* horiz = (const float*)d_in[2];
  float* out = (float*)d_out;

  dim3 grid(WW / TILE_W, HH / TILE_H, NB * NC);   // 8 x 32 x 6 = 1536 blocks x 256 threads
  sepconv_kernel<<<grid, NTHREADS, 0, stream>>>(inp, vert, horiz, out);
}

// Round 4
// 321.684 us; speedup vs baseline: 5.1957x; 5.1957x over previous
//
#include <hip/hip_runtime.h>

// Adaptive separable conv (SepConv): out[b,c,y,x] = sum_i sum_j inp[b,c,y+i,x+j]*v[b,i,y,x]*h[b,j,y,x]
// B=2,C=3,H=W=256,K=51. fp32 in/out. No MFMA path (per-pixel weights; no fp32 MFMA on CDNA4).
//
// R4: remove the occupancy hint. R1(launch_bounds 512,4) / R2(waves_per_eu 4,4) /
// R3(launch_bounds 256,4) ALL produced VGPR=64 + heavy scratch spill (WRITE_SIZE up to
// 2.9GB vs 1.5MB of output): the backend chases the MAX of the waves-per-eu range implied
// by the hint and spills to reach the 64-reg/8-wave bucket. R0's (256,1) is the known-good
// allocator path (VGPR=172, zero spill). So: same structure as R3 (1 channel/block,
// LDS 19.5KB, live set ~84 floats, separable 1.25 ops/MAC factorization, NS=4 i-split),
// but launch_bounds(256,1) -> natural allocation ~95-115 VGPR -> 4 waves/SIMD at
// 4 blocks/CU with zero spill (LDS allows 8 blocks; VGPR is the binding resource).

namespace {
constexpr int KK = 51;
constexpr int NB = 2;
constexpr int NC = 3;
constexpr int HH = 256;
constexpr int WW = 256;
constexpr int IN_H = HH + KK - 1;   // 306
constexpr int IN_W = WW + KK - 1;   // 306

constexpr int TILE_W = 32;          // output cols per block
constexpr int TILE_H = 8;           // output rows per block
constexpr int NTX = 8;              // threads along x (each covers R=4 outputs)
constexpr int R = 4;
constexpr int NTY = 8;
constexpr int NS = 4;               // i-tap split (one range per wave)
constexpr int NTHREADS = NTX * NTY * NS;   // 256
constexpr int HALO_W = TILE_W + KK - 1;  // 82
constexpr int LDS_W = 84;           // 82 valid + 2 zero-pad cols
constexpr int LDS_H = TILE_H + KK - 1;   // 58
constexpr int BI = 4;               // i-taps per register block
constexpr int KSTRIDE = HH * WW;    // per-tap stride in v/h
}

__device__ __forceinline__ float fget(const float4 v, int i) {
  return (i == 0) ? v.x : (i == 1) ? v.y : (i == 2) ? v.z : v.w;
}

__global__ __launch_bounds__(NTHREADS, 1)   // min-blocks=1: known-good allocator path (R0)
void sepconv_kernel(
    const float* __restrict__ inp,
    const float* __restrict__ vert,
    const float* __restrict__ horiz,
    float* __restrict__ out)
{
  __shared__ float lds[LDS_H * LDS_W];   // 19,488 B

  const int tid = threadIdx.x;
  const int tx  = tid & (NTX - 1);
  const int ty  = (tid >> 3) & (NTY - 1);
  const int s   = tid >> 6;                    // wave id: 0..3 (wave-uniform)

  const int x0 = blockIdx.x * TILE_W;
  const int y0 = blockIdx.y * TILE_H;
  const int bc = blockIdx.z;                   // 0..5
  const int b  = bc / NC;
  const int c  = bc % NC;

  // ---- Stage input tile: 1ch x 58 rows x 82 cols (float2), zero the 2 pad cols.
  {
    const float* src = inp + (((size_t)(b * NC + c)) * IN_H + y0) * IN_W + x0;
    constexpr int total2 = LDS_H * (HALO_W / 2);   // 58*41 = 2378
    for (int e = tid; e < total2; e += NTHREADS) {
      const int col2 = e % (HALO_W / 2);
      const int r    = e / (HALO_W / 2);
      const float2 v = *reinterpret_cast<const float2*>(src + (size_t)r * IN_W + col2 * 2);
      float* dst = &lds[r * LDS_W + col2 * 2];
      dst[0] = v.x; dst[1] = v.y;
    }
    for (int e = tid; e < LDS_H * 2; e += NTHREADS) {
      const int r = e >> 1;
      const int p = e & 1;
      lds[r * LDS_W + HALO_W + p] = 0.0f;
    }
  }
  __syncthreads();

  const int lx = tx * R;                 // local LDS col base (16B aligned)
  const int xg = x0 + lx;                // global x of first output
  const int yg = y0 + ty;                // global y

  float acc[R] = {0.f, 0.f, 0.f, 0.f};

  // i-tap split: s<3 -> 13 taps (3 BI=4 blocks + 1 tail), s==3 -> taps 39..50 (3 blocks)
  const int sb = (s < 3) ? 13 * s : 39;
  const bool has_tail = (s < 3);

  const float* vbase = vert  + (((size_t)b * KK) * HH + yg) * WW + xg;
  const float* hbase = horiz + (((size_t)b * KK) * HH + yg) * WW + xg;

  for (int i0 = 0; i0 < 3; ++i0) {       // uniform across all waves; all taps valid
    const int ibase = sb + i0 * BI;

    // Vertical weights for this block (read-once).
    float4 v4[BI];
#pragma unroll
    for (int ib = 0; ib < BI; ++ib)
      v4[ib] = *reinterpret_cast<const float4*>(vbase + (size_t)(ibase + ib) * KSTRIDE);

    // Rolling windows: w[ib] = inp row (ty+ibase+ib), cols [lx, lx+8)
    float w[BI][8];
#pragma unroll
    for (int ib = 0; ib < BI; ++ib) {
      const int rr = ty + ibase + ib;    // <= 7 + 50 = 57, in bounds
      const float4* p = reinterpret_cast<const float4*>(&lds[rr * LDS_W + lx]);
      const float4 a = p[0], bq = p[1];
      w[ib][0] = a.x;  w[ib][1] = a.y;  w[ib][2] = a.z;  w[ib][3] = a.w;
      w[ib][4] = bq.x; w[ib][5] = bq.y; w[ib][6] = bq.z; w[ib][7] = bq.w;
    }

    // h for chunk j0=0 (taps 0..3)
    float4 h4[4];
#pragma unroll
    for (int jj = 0; jj < 4; ++jj)
      h4[jj] = *reinterpret_cast<const float4*>(hbase + (size_t)jj * KSTRIDE);

    for (int j0 = 0; j0 < 52; j0 += 4) {   // 13 chunks of 4 j-taps
#pragma unroll
      for (int jj = 0; jj < 4; ++jj) {
        // t = sum_ib v[ib]*w[ib][rx+jj]; acc += h*t  -> (BI+1) ops per BI MACs
#pragma unroll
        for (int rx = 0; rx < R; ++rx) {
          float t = fget(v4[0], rx) * w[0][rx + jj];
#pragma unroll
          for (int ib = 1; ib < BI; ++ib)
            t = fmaf(fget(v4[ib], rx), w[ib][rx + jj], t);
          acc[rx] = fmaf(fget(h4[jj], rx), t, acc[rx]);
        }
        // In-place prefetch of next chunk's tap jj (clamped; dead on last chunk, harmless).
        const int j  = j0 + 4 + jj;
        const int jc = (j <= 50) ? j : 50;
        float4 t4 = *reinterpret_cast<const float4*>(hbase + (size_t)jc * KSTRIDE);
        if (j > 50) t4 = make_float4(0.f, 0.f, 0.f, 0.f);
        h4[jj] = t4;
      }

      // Rotate windows; read next quad (max col = 38+44+... <= 83, zero pad region).
      if (j0 < 48) {
#pragma unroll
        for (int ib = 0; ib < BI; ++ib) {
          const int rr = ty + ibase + ib;
#pragma unroll
          for (int q = 0; q < 4; ++q) w[ib][q] = w[ib][q + 4];
          const float4 n = *reinterpret_cast<const float4*>(&lds[rr * LDS_W + lx + j0 + 8]);
          w[ib][4] = n.x; w[ib][5] = n.y; w[ib][6] = n.z; w[ib][7] = n.w;
        }
      }
    }
  }

  // ---- BI=1 tail: 13th tap for s<3 (i = sb+12; 2 ops/MAC but only 1/13 of work)
  if (has_tail) {
    const int i = sb + 12;               // 12, 25, 38
    const float4 v1 = *reinterpret_cast<const float4*>(vbase + (size_t)i * KSTRIDE);
    const int rr = ty + i;               // <= 45
    float w1[8];
    {
      const float4* p = reinterpret_cast<const float4*>(&lds[rr * LDS_W + lx]);
      const float4 a = p[0], bq = p[1];
      w1[0] = a.x;  w1[1] = a.y;  w1[2] = a.z;  w1[3] = a.w;
      w1[4] = bq.x; w1[5] = bq.y; w1[6] = bq.z; w1[7] = bq.w;
    }
    float4 h4[4];
#pragma unroll
    for (int jj = 0; jj < 4; ++jj)
      h4[jj] = *reinterpret_cast<const float4*>(hbase + (size_t)jj * KSTRIDE);

    for (int j0 = 0; j0 < 52; j0 += 4) {
#pragma unroll
      for (int jj = 0; jj < 4; ++jj) {
#pragma unroll
        for (int rx = 0; rx < R; ++rx)
          acc[rx] = fmaf(fget(v1, rx) * fget(h4[jj], rx), w1[rx + jj], acc[rx]);
        const int j  = j0 + 4 + jj;
        const int jc = (j <= 50) ? j : 50;
        float4 t4 = *reinterpret_cast<const float4*>(hbase + (size_t)jc * KSTRIDE);
        if (j > 50) t4 = make_float4(0.f, 0.f, 0.f, 0.f);
        h4[jj] = t4;
      }
      if (j0 < 48) {
#pragma unroll
        for (int q = 0; q < 4; ++q) w1[q] = w1[q + 4];
        const float4 n = *reinterpret_cast<const float4*>(&lds[rr * LDS_W + lx + j0 + 8]);
        w1[4] = n.x; w1[5] = n.y; w1[6] = n.z; w1[7] = n.w;
      }
    }
  }

  // ---- Reduce the 4 i-split partials (waves 1..3 -> LDS, wave 0 adds & stores)
  __syncthreads();   // all LDS inp reads done; safe to reuse (3*64*4*4B = 3KB)
  if (s > 0) {
    float* p = &lds[((s - 1) * 64 + ty * NTX + tx) * 4];
#pragma unroll
    for (int rx = 0; rx < R; ++rx) p[rx] = acc[rx];
  }
  __syncthreads();
  if (s == 0) {
#pragma unroll
    for (int g = 0; g < 3; ++g) {
      const float* p = &lds[(g * 64 + ty * NTX + tx) * 4];
#pragma unroll
      for (int rx = 0; rx < R; ++rx) acc[rx] += p[rx];
    }
    const float4 o = make_float4(acc[0], acc[1], acc[2], acc[3]);
    *reinterpret_cast<float4*>(out + (((size_t)(b * NC + c)) * HH + yg) * WW + xg) = o;
  }
}

extern "C" void kernel_launch(void* const* d_in, const int* in_sizes, int n_in,
                              void* d_out, int out_size, void* d_ws, size_t ws_size,
                              hipStream_t stream) {
  const float* inp   = (const float*)d_in[0];
  const float* vert  = (const float*)d_in[1];
  const float* horiz = (const float*)d_in[2];
  float* out = (float*)d_out;

  dim3 grid(WW / TILE_W, HH / TILE_H, NB * NC);   // 8 x 32 x 6 = 1536 blocks x 256 threads
  sepconv_kernel<<<grid, NTHREADS, 0, stream>>>(inp, vert, horiz, out);
}

// Round 5
// 158.990 us; speedup vs baseline: 10.5124x; 2.0233x over previous
//
#include <hip/hip_runtime.h>

// Adaptive separable conv (SepConv): out[b,c,y,x] = sum_i sum_j inp[b,c,y+i,x+j]*v[b,i,y,x]*h[b,j,y,x]
// B=2,C=3,H=W=256,K=51. fp32 in/out. No MFMA path (per-pixel weights; no fp32 MFMA on CDNA4).
//
// R5: allocator-friendly rewrite. R1-R4 all spilled (WRITE_SIZE 150MB-2.9GB) regardless of
// occupancy hints; structural suspects were (a) clamped in-place h prefetch in the unrolled
// jj loop, (b) a duplicated BI=1 tail region, (c) compiler-unrolled outer loops. This version:
//  - ONE uniform code region: 52 virtual taps = 13 BI=4 blocks dealt to 4 waves (4/3/3/3);
//    tap 51 is v=0-masked + row-clamped (2% waste, no tail code).
//  - No conditionals in the hot loop: 12 clean j-chunks (j<48) + 3-tap epilogue.
//  - #pragma unroll 1 on the runtime loops; live set ~90 floats.
//  - launch_bounds(256,1); NS=4 i-split keeps 6144 waves (6/SIMD oversubscription).
// LDS 19.5KB/block; separable t = sum_ib v*w, acc += h*t (1.25 ops/MAC).

namespace {
constexpr int KK = 51;
constexpr int NB = 2;
constexpr int NC = 3;
constexpr int HH = 256;
constexpr int WW = 256;
constexpr int IN_H = HH + KK - 1;   // 306
constexpr int IN_W = WW + KK - 1;   // 306

constexpr int TILE_W = 32;          // output cols per block
constexpr int TILE_H = 8;           // output rows per block
constexpr int NTX = 8;              // threads along x (each covers R=4 outputs)
constexpr int R = 4;
constexpr int NTY = 8;
constexpr int NS = 4;               // i-tap split (one block-range per wave)
constexpr int NTHREADS = NTX * NTY * NS;   // 256
constexpr int HALO_W = TILE_W + KK - 1;  // 82
constexpr int LDS_W = 84;           // 82 valid + 2 zero-pad cols
constexpr int LDS_H = TILE_H + KK - 1;   // 58
constexpr int KSTRIDE = HH * WW;    // per-tap stride in v/h (65536)
}

__device__ __forceinline__ float fget(const float4 v, int i) {
  return (i == 0) ? v.x : (i == 1) ? v.y : (i == 2) ? v.z : v.w;
}

__global__ __launch_bounds__(NTHREADS, 1)
void sepconv_kernel(
    const float* __restrict__ inp,
    const float* __restrict__ vert,
    const float* __restrict__ horiz,
    float* __restrict__ out)
{
  __shared__ float lds[LDS_H * LDS_W];   // 19,488 B

  const int tid = threadIdx.x;
  const int tx  = tid & (NTX - 1);
  const int ty  = (tid >> 3) & (NTY - 1);
  const int s   = tid >> 6;                    // wave id: 0..3 (wave-uniform)

  const int x0 = blockIdx.x * TILE_W;
  const int y0 = blockIdx.y * TILE_H;
  const int bc = blockIdx.z;                   // 0..5
  const int b  = bc / NC;
  const int c  = bc % NC;

  // ---- Stage input tile: 1ch x 58 rows x 82 cols (float2), zero the 2 pad cols.
  {
    const float* src = inp + (((size_t)(b * NC + c)) * IN_H + y0) * IN_W + x0;
    constexpr int total2 = LDS_H * (HALO_W / 2);   // 58*41 = 2378
    for (int e = tid; e < total2; e += NTHREADS) {
      const int col2 = e % (HALO_W / 2);
      const int r    = e / (HALO_W / 2);
      const float2 v = *reinterpret_cast<const float2*>(src + (size_t)r * IN_W + col2 * 2);
      float* dst = &lds[r * LDS_W + col2 * 2];
      dst[0] = v.x; dst[1] = v.y;
    }
    for (int e = tid; e < LDS_H * 2; e += NTHREADS) {
      const int r = e >> 1;
      const int p = e & 1;
      lds[r * LDS_W + HALO_W + p] = 0.0f;
    }
  }
  __syncthreads();

  const int lx = tx * R;                 // local LDS col base (16B aligned)
  const int xg = x0 + lx;                // global x of first output
  const int yg = y0 + ty;                // global y

  float acc[R] = {0.f, 0.f, 0.f, 0.f};

  // Deal 13 BI=4 tap-blocks (52 virtual taps; tap 51 masked) to 4 waves: 4/3/3/3.
  const int blk0 = (s == 0) ? 0 : (3 * s + 1);   // 0,4,7,10
  const int nblk = (s == 0) ? 4 : 3;

  const float* vbase = vert  + (((size_t)b * KK) * HH + yg) * WW + xg;
  const float* hbase = horiz + (((size_t)b * KK) * HH + yg) * WW + xg;

#pragma unroll 1
  for (int t = 0; t < nblk; ++t) {
    const int ibase = (blk0 + t) * 4;    // 0..48

    // Vertical weights + initial windows for the 4 taps of this block.
    float4 v4[4];
    float  w[4][8];
#pragma unroll
    for (int ib = 0; ib < 4; ++ib) {
      const int iv = ibase + ib;                 // <= 51
      const int ic = (iv <= 50) ? iv : 50;       // clamp row for masked tap
      float4 vv = *reinterpret_cast<const float4*>(vbase + (size_t)ic * KSTRIDE);
      if (iv > 50) vv = make_float4(0.f, 0.f, 0.f, 0.f);
      v4[ib] = vv;
      const int rr = ty + ic;                    // <= 7 + 50 = 57
      const float4* p = reinterpret_cast<const float4*>(&lds[rr * LDS_W + lx]);
      const float4 a = p[0], bq = p[1];
      w[ib][0] = a.x;  w[ib][1] = a.y;  w[ib][2] = a.z;  w[ib][3] = a.w;
      w[ib][4] = bq.x; w[ib][5] = bq.y; w[ib][6] = bq.z; w[ib][7] = bq.w;
    }

    const float* hp = hbase;             // walks 4 taps per chunk

#pragma unroll 1
    for (int j0 = 0; j0 < 48; j0 += 4) {   // 12 clean chunks (j = 0..47, no masking)
      float4 h4[4];
#pragma unroll
      for (int jj = 0; jj < 4; ++jj)
        h4[jj] = *reinterpret_cast<const float4*>(hp + (size_t)jj * KSTRIDE);

      // t = sum_ib v[ib]*w[ib][rx+jj]; acc += h*t  -> 5 ops per 4 MACs
#pragma unroll
      for (int jj = 0; jj < 4; ++jj) {
#pragma unroll
        for (int rx = 0; rx < R; ++rx) {
          float tv = fget(v4[0], rx) * w[0][rx + jj];
          tv = fmaf(fget(v4[1], rx), w[1][rx + jj], tv);
          tv = fmaf(fget(v4[2], rx), w[2][rx + jj], tv);
          tv = fmaf(fget(v4[3], rx), w[3][rx + jj], tv);
          acc[rx] = fmaf(fget(h4[jj], rx), tv, acc[rx]);
        }
      }

      // Rotate windows; read next quad (max col = 28+44+8+3 = 83, zero-pad region).
      const int rbase = lx + j0 + 8;
#pragma unroll
      for (int ib = 0; ib < 4; ++ib) {
        const int iv = ibase + ib;
        const int ic = (iv <= 50) ? iv : 50;
        const int rr = ty + ic;
#pragma unroll
        for (int q = 0; q < 4; ++q) w[ib][q] = w[ib][q + 4];
        const float4 n = *reinterpret_cast<const float4*>(&lds[rr * LDS_W + rbase]);
        w[ib][4] = n.x; w[ib][5] = n.y; w[ib][6] = n.z; w[ib][7] = n.w;
      }
      hp += (size_t)4 * KSTRIDE;
    }

    // Epilogue: j = 48,49,50 (window holds cols [48,56) after the 12th rotate).
    {
      float4 h4e[3];
#pragma unroll
      for (int jj = 0; jj < 3; ++jj)
        h4e[jj] = *reinterpret_cast<const float4*>(hp + (size_t)jj * KSTRIDE);
#pragma unroll
      for (int jj = 0; jj < 3; ++jj) {
#pragma unroll
        for (int rx = 0; rx < R; ++rx) {
          float tv = fget(v4[0], rx) * w[0][rx + jj];
          tv = fmaf(fget(v4[1], rx), w[1][rx + jj], tv);
          tv = fmaf(fget(v4[2], rx), w[2][rx + jj], tv);
          tv = fmaf(fget(v4[3], rx), w[3][rx + jj], tv);
          acc[rx] = fmaf(fget(h4e[jj], rx), tv, acc[rx]);
        }
      }
    }
  }

  // ---- Reduce the 4 i-split partials (waves 1..3 -> LDS, wave 0 adds & stores)
  __syncthreads();   // all LDS inp reads done; safe to reuse (3*64*4*4B = 3KB)
  if (s > 0) {
    float* p = &lds[((s - 1) * 64 + ty * NTX + tx) * 4];
#pragma unroll
    for (int rx = 0; rx < R; ++rx) p[rx] = acc[rx];
  }
  __syncthreads();
  if (s == 0) {
#pragma unroll
    for (int g = 0; g < 3; ++g) {
      const float* p = &lds[(g * 64 + ty * NTX + tx) * 4];
#pragma unroll
      for (int rx = 0; rx < R; ++rx) acc[rx] += p[rx];
    }
    const float4 o = make_float4(acc[0], acc[1], acc[2], acc[3]);
    *reinterpret_cast<float4*>(out + (((size_t)(b * NC + c)) * HH + yg) * WW + xg) = o;
  }
}

extern "C" void kernel_launch(void* const* d_in, const int* in_sizes, int n_in,
                              void* d_out, int out_size, void* d_ws, size_t ws_size,
                              hipStream_t stream) {
  const float* inp   = (const float*)d_in[0];
  const float* vert  = (const float*)d_in[1];
  const float* horiz = (const float*)d_in[2];
  float* out = (float*)d_out;

  dim3 grid(WW / TILE_W, HH / TILE_H, NB * NC);   // 8 x 32 x 6 = 1536 blocks x 256 threads
  sepconv_kernel<<<grid, NTHREADS, 0, stream>>>(inp, vert, horiz, out);
}